// Round 16
// baseline (1457.191 us; speedup 1.0000x reference)
//
#include <hip/hip_runtime.h>
#include <math.h>

#define NN 50000
#define NE 800000
#define NG 64
#define DIN 64
#define DEA 16
#define H 128
#define NL 4
#define EPB 128   // edges per block in edge_mfma_kernel
#define MAXD 12   // LDS dst-slot rows (6KB; total 38.9KB)

typedef __attribute__((ext_vector_type(8))) short short8;
typedef __attribute__((ext_vector_type(4))) float f32x4;

__device__ __forceinline__ float4 ld4(const float* p) { return *reinterpret_cast<const float4*>(p); }
__device__ __forceinline__ void st4(float* p, float4 v) { *reinterpret_cast<float4*>(p) = v; }
__device__ __forceinline__ void fma4(float4& a, float s, float4 w) {
    a.x = fmaf(s, w.x, a.x); a.y = fmaf(s, w.y, a.y);
    a.z = fmaf(s, w.z, a.z); a.w = fmaf(s, w.w, a.w);
}
__device__ __forceinline__ float4 f4add(float4 a, float4 b) {
    return make_float4(a.x + b.x, a.y + b.y, a.z + b.z, a.w + b.w);
}
__device__ __forceinline__ float4 relu4(float4 a) {
    return make_float4(fmaxf(a.x, 0.f), fmaxf(a.y, 0.f), fmaxf(a.z, 0.f), fmaxf(a.w, 0.f));
}
__device__ __forceinline__ unsigned fkey(float f) {
    unsigned b = __float_as_uint(f);
    return (b & 0x80000000u) ? ~b : (b | 0x80000000u);
}
__device__ __forceinline__ float funkey(unsigned k) {
    unsigned b = (k & 0x80000000u) ? (k ^ 0x80000000u) : ~k;
    return __uint_as_float(b);
}
__device__ __forceinline__ ushort f2bf(float f) {
    unsigned u = __float_as_uint(f);
    return (ushort)((u + 0x7fffu + ((u >> 16) & 1u)) >> 16);
}
__device__ __forceinline__ float bf2f(ushort b) {
    return __uint_as_float(((unsigned)b) << 16);
}

// h = relu(x @ encW + encb), x:[NN,64], W:[64,128]
__global__ __launch_bounds__(256) void encoder_kernel(const float* __restrict__ x,
    const float* __restrict__ W, const float* __restrict__ b, float* __restrict__ h)
{
    const int tid = threadIdx.x, q = tid & 31, no = tid >> 5;
    const int nbase = blockIdx.x * 64;
    float4 bv = ld4(b + 4 * q);
    float4 acc[8];
#pragma unroll
    for (int i = 0; i < 8; ++i) acc[i] = bv;
    for (int k4 = 0; k4 < 16; ++k4) {
        const float* wp = W + (4 * k4) * H + 4 * q;
        float4 w0 = ld4(wp), w1 = ld4(wp + H), w2 = ld4(wp + 2 * H), w3 = ld4(wp + 3 * H);
#pragma unroll
        for (int i = 0; i < 8; ++i) {
            int n = nbase + no * 8 + i; n = n < NN ? n : NN - 1;
            float4 a = ld4(x + n * DIN + 4 * k4);
            fma4(acc[i], a.x, w0); fma4(acc[i], a.y, w1);
            fma4(acc[i], a.z, w2); fma4(acc[i], a.w, w3);
        }
    }
#pragma unroll
    for (int i = 0; i < 8; ++i) {
        int n = nbase + no * 8 + i;
        if (n < NN) st4(h + n * H + 4 * q, relu4(acc[i]));
    }
}

__global__ __launch_bounds__(256) void dist2_kernel(const float* __restrict__ pos,
    const int* __restrict__ ei, float* __restrict__ d2)
{
    int e = blockIdx.x * 256 + threadIdx.x;
    if (e >= NE) return;
    int s = ei[e], d = ei[NE + e];
    float dx = pos[s * 3 + 0] - pos[d * 3 + 0];
    float dy = pos[s * 3 + 1] - pos[d * 3 + 1];
    float dz = pos[s * 3 + 2] - pos[d * 3 + 2];
    d2[e] = dx * dx + dy * dy + dz * dz;
}

// ---------- counting sort of edges by dst ----------
__global__ __launch_bounds__(256) void hist_kernel(const int* __restrict__ ei, int* __restrict__ deg)
{
    int e = blockIdx.x * 256 + threadIdx.x;
    if (e < NE) atomicAdd(&deg[ei[NE + e]], 1);
}

__global__ __launch_bounds__(1024) void scan_kernel(const int* __restrict__ deg, int* __restrict__ cursor)
{
    __shared__ int tot[1024];
    const int t = threadIdx.x;
    const int CH = (NN + 1023) / 1024;
    const int base = t * CH;
    int s = 0;
    for (int i = 0; i < CH; ++i) {
        int idx = base + i;
        if (idx < NN) s += deg[idx];
    }
    tot[t] = s;
    __syncthreads();
    for (int off = 1; off < 1024; off <<= 1) {
        int v = (t >= off) ? tot[t - off] : 0;
        __syncthreads();
        tot[t] += v;
        __syncthreads();
    }
    int run = (t == 0) ? 0 : tot[t - 1];
    for (int i = 0; i < CH; ++i) {
        int idx = base + i;
        if (idx < NN) { cursor[idx] = run; run += deg[idx]; }
    }
}

__global__ __launch_bounds__(256) void scatter_kernel(const int* __restrict__ ei,
    const float* __restrict__ ea, const float* __restrict__ d2, int* __restrict__ cursor,
    int* __restrict__ src_s, int* __restrict__ dst_s,
    float* __restrict__ ea_s, float* __restrict__ d2_s)
{
    int e = blockIdx.x * 256 + threadIdx.x;
    if (e >= NE) return;
    int s = ei[e], d = ei[NE + e];
    int pos = atomicAdd(&cursor[d], 1);
    src_s[pos] = s; dst_s[pos] = d; d2_s[pos] = d2[e];
    const float4* ev = reinterpret_cast<const float4*>(ea + (size_t)e * DEA);
    float4* ov = reinterpret_cast<float4*>(ea_s + (size_t)pos * DEA);
    ov[0] = ev[0]; ov[1] = ev[1]; ov[2] = ev[2]; ov[3] = ev[3];
}

// ---------- generic W [K x 128] -> split bf16 (hi+lo), transposed [n][k], k-panel-64 swizzled ----------
__global__ __launch_bounds__(256) void wprep_kernel(const float* __restrict__ W,
    ushort* __restrict__ hi, ushort* __restrict__ lo,
    int K, int in_lstride, int out_lstride)
{
    int l = blockIdx.y;
    const float* Wb = W + (size_t)l * in_lstride;
    ushort* hg = hi + (size_t)l * out_lstride;
    ushort* lg = lo + (size_t)l * out_lstride;
    int total = K * 128;
    for (int idx = blockIdx.x * 256 + threadIdx.x; idx < total; idx += gridDim.x * 256) {
        int k = idx >> 7, n = idx & 127;
        float wv = Wb[idx];
        ushort hb = f2bf(wv);
        float rem = wv - bf2f(hb);
        ushort lb = f2bf(rem);
        int panel = k >> 6, kk = k & 63;
        int pos = panel * 8192 + (n << 6) + (kk ^ ((n & 7) << 3));
        hg[pos] = hb; lg[pos] = lb;
    }
}

// ---------- proj (layer 0 only): Pdb = bf16(h@W1d + b1), Psb = bf16(h@W1s) ----------
__global__ __launch_bounds__(512, 4) void proj_mfma_kernel(const float* __restrict__ h,
    const ushort* __restrict__ wdh, const ushort* __restrict__ wdl,
    const ushort* __restrict__ wsh, const ushort* __restrict__ wsl,
    const float* __restrict__ b1,
    ushort* __restrict__ Pdb, ushort* __restrict__ Psb)
{
    __shared__ __align__(16) ushort Afull[128 * 128];
    __shared__ __align__(16) ushort Wh[128 * 64];
    __shared__ __align__(16) ushort Wl[128 * 64];
    const int tid = threadIdx.x;
    const int nbase = blockIdx.x * 128;

    {
        int r = tid >> 2, kq = (tid & 3) * 32;
        int n = nbase + r; n = n < NN ? n : NN - 1;
        const float* src = h + (size_t)n * H + kq;
        int swz = (r & 7) << 3;
#pragma unroll
        for (int j = 0; j < 4; ++j) {
            float4 a = ld4(src + 8 * j);
            float4 b = ld4(src + 8 * j + 4);
            union { ushort u[8]; int4 v; } pk;
            pk.u[0] = f2bf(a.x); pk.u[1] = f2bf(a.y); pk.u[2] = f2bf(a.z); pk.u[3] = f2bf(a.w);
            pk.u[4] = f2bf(b.x); pk.u[5] = f2bf(b.y); pk.u[6] = f2bf(b.z); pk.u[7] = f2bf(b.w);
            *reinterpret_cast<int4*>(&Afull[r * 128 + ((kq + 8 * j) ^ swz)]) = pk.v;
        }
    }

    const int lane = tid & 63, wvx = tid >> 6, colL = lane & 15, g = lane >> 4;
    const int arow = wvx * 16 + colL, aswz = (arow & 7) << 3;
    f32x4 accd[8], accs[8];
#pragma unroll
    for (int nt = 0; nt < 8; ++nt) { accd[nt] = (f32x4){0, 0, 0, 0}; accs[nt] = (f32x4){0, 0, 0, 0}; }

#define PROJ_ROUND(ABUF, HSRC, LSRC, KOFF, ACC)                                         \
    {                                                                                   \
        ((int4*)Wh)[tid] = ((const int4*)(HSRC))[tid];                                  \
        ((int4*)Wh)[tid + 512] = ((const int4*)(HSRC))[tid + 512];                      \
        ((int4*)Wl)[tid] = ((const int4*)(LSRC))[tid];                                  \
        ((int4*)Wl)[tid + 512] = ((const int4*)(LSRC))[tid + 512];                      \
        __syncthreads();                                                                \
        _Pragma("unroll")                                                               \
        for (int ks = 0; ks < 2; ++ks) {                                                \
            int kk0 = ks * 32;                                                          \
            short8 af = *(const short8*)&ABUF[arow * 128 + (((KOFF) + kk0 + 8 * g) ^ aswz)]; \
            _Pragma("unroll")                                                           \
            for (int nt = 0; nt < 8; ++nt) {                                            \
                int brow = nt * 16 + colL;                                              \
                int bidx = brow * 64 + ((kk0 + 8 * g) ^ ((brow & 7) << 3));             \
                short8 bh = *(const short8*)&Wh[bidx];                                  \
                short8 bl = *(const short8*)&Wl[bidx];                                  \
                ACC[nt] = __builtin_amdgcn_mfma_f32_16x16x32_bf16(af, bh, ACC[nt], 0, 0, 0); \
                ACC[nt] = __builtin_amdgcn_mfma_f32_16x16x32_bf16(af, bl, ACC[nt], 0, 0, 0); \
            }                                                                           \
        }                                                                               \
        __syncthreads();                                                                \
    }

    PROJ_ROUND(Afull, wdh, wdl, 0, accd)
    PROJ_ROUND(Afull, wdh + 8192, wdl + 8192, 64, accd)
    PROJ_ROUND(Afull, wsh, wsl, 0, accs)
    PROJ_ROUND(Afull, wsh + 8192, wsl + 8192, 64, accs)

    float b1r[8];
#pragma unroll
    for (int nt = 0; nt < 8; ++nt) b1r[nt] = b1[nt * 16 + colL];

    const int rowb = wvx * 16 + g * 4;
#pragma unroll
    for (int r = 0; r < 4; ++r) {
        int n = nbase + rowb + r;
        if (n < NN) {
#pragma unroll
            for (int nt = 0; nt < 8; ++nt) {
                Pdb[(size_t)n * H + nt * 16 + colL] = f2bf(accd[nt][r] + b1r[nt]);
                Psb[(size_t)n * H + nt * 16 + colL] = f2bf(accs[nt][r]);
            }
        }
    }
}

// dst-sorted edges, 128 edges/block, 8 waves. XCD-chunked bijective block swizzle.
// W2 col-slice register loads hoisted to kernel start (overlap with gather latency).
// stage1: t = relu(Pdb[dst]+Psb[src]+d2*wd+ea@Wea) -> bf16 swizzled LDS
// stage2: wave owns 16 output cols, W2 col-slice in registers
// reduce: run-reduce -> LDS accb[dst-dfirst] (MAXD=12; fallback global atomic) ->
//         interior rows plain store, boundary rows atomicAdd.
__global__ __launch_bounds__(512, 4) void edge_mfma_kernel(
    const ushort* __restrict__ Pdb, const ushort* __restrict__ Psb,
    const float* __restrict__ ea_s, const float* __restrict__ d2_s,
    const int* __restrict__ src_s, const int* __restrict__ dst_s,
    const float* __restrict__ W1,
    const ushort* __restrict__ w2hiL, const ushort* __restrict__ w2loL,
    const float* __restrict__ b2, float* __restrict__ agg)
{
    __shared__ __align__(16) ushort tls[EPB * H];   // 32KB
    __shared__ __align__(16) float accb[MAXD * H];  // 6KB

    // bijective XCD chunked swizzle (m204): nwg = NE/EPB = 6250, 8 XCDs
    const int NWG = NE / EPB, QQ = NWG / 8, RR = NWG % 8;
    int orig = blockIdx.x;
    int xcd = orig & 7, ixc = orig >> 3;
    int bswz = (xcd < RR ? xcd * (QQ + 1) : RR * (QQ + 1) + (xcd - RR) * QQ) + ixc;

    const int tid = threadIdx.x, q = tid & 31, eo = tid >> 5;
    const int ebase = bswz * EPB;
    const int lane = tid & 63, wv = tid >> 6;
    const int col = lane & 15, g = lane >> 4;

    // ---- hoisted: wave's W2^T col-slice (hi+lo) into registers + b2 ----
    const int nW = wv * 16 + col;
    const int nswz = (nW & 7) << 3;
    short8 bh[4], bl[4];
#pragma unroll
    for (int ks = 0; ks < 4; ++ks) {
        int kkg = ks * 32 + 8 * g;
        int panel = kkg >> 6, kk = kkg & 63;
        int pos = panel * 8192 + nW * 64 + (kk ^ nswz);
        bh[ks] = *reinterpret_cast<const short8*>(&w2hiL[pos]);
        bl[ks] = *reinterpret_cast<const short8*>(&w2loL[pos]);
    }
    float b2r = b2[nW];

    // zero accb (MAXD*H = 1536 floats)
    if (tid < (MAXD * H) / 4) st4(&accb[tid * 4], make_float4(0.f, 0.f, 0.f, 0.f));

    // block dst range + boundary info (uniform scalar loads)
    const int dfirst = dst_s[ebase];
    const int dlast  = dst_s[ebase + EPB - 1];
    const int dprev  = (ebase > 0) ? dst_s[ebase - 1] : -1;
    const int dnext  = (ebase + EPB < NE) ? dst_s[ebase + EPB] : -1;

    // ---- stage 1: edge MLP layer-1 (fp32, bf16 gathers) ----
    const float* Wea = W1 + 256 * H;
    const float* wdv = W1 + 272 * H;
    float4 wdq = ld4(wdv + 4 * q);

    int srcs[8], dsts8[8];
    float d2v[8];
#pragma unroll
    for (int i = 0; i < 8; ++i) {
        int j = ebase + eo * 8 + i;
        srcs[i] = src_s[j]; dsts8[i] = dst_s[j]; d2v[i] = d2_s[j];
    }
    float4 acc1[8];
#pragma unroll
    for (int i = 0; i < 8; ++i) {
        ushort4 pd4 = *reinterpret_cast<const ushort4*>(&Pdb[(size_t)dsts8[i] * H + 4 * q]);
        ushort4 ps4 = *reinterpret_cast<const ushort4*>(&Psb[(size_t)srcs[i] * H + 4 * q]);
        float4 a;
        a.x = bf2f(pd4.x) + bf2f(ps4.x);
        a.y = bf2f(pd4.y) + bf2f(ps4.y);
        a.z = bf2f(pd4.z) + bf2f(ps4.z);
        a.w = bf2f(pd4.w) + bf2f(ps4.w);
        fma4(a, d2v[i], wdq);
        acc1[i] = a;
    }
#pragma unroll
    for (int k4 = 0; k4 < 4; ++k4) {
        float4 w0 = ld4(Wea + (4 * k4 + 0) * H + 4 * q);
        float4 w1 = ld4(Wea + (4 * k4 + 1) * H + 4 * q);
        float4 w2 = ld4(Wea + (4 * k4 + 2) * H + 4 * q);
        float4 w3 = ld4(Wea + (4 * k4 + 3) * H + 4 * q);
#pragma unroll
        for (int i = 0; i < 8; ++i) {
            int j = ebase + eo * 8 + i;
            float4 av = ld4(ea_s + (size_t)j * DEA + 4 * k4);
            fma4(acc1[i], av.x, w0); fma4(acc1[i], av.y, w1);
            fma4(acc1[i], av.z, w2); fma4(acc1[i], av.w, w3);
        }
    }
#pragma unroll
    for (int i = 0; i < 8; ++i) {
        int el = eo * 8 + i;
        ushort4 tv;
        tv.x = f2bf(fmaxf(acc1[i].x, 0.f)); tv.y = f2bf(fmaxf(acc1[i].y, 0.f));
        tv.z = f2bf(fmaxf(acc1[i].z, 0.f)); tv.w = f2bf(fmaxf(acc1[i].w, 0.f));
        int tidx = el * H + ((4 * q) ^ ((el & 7) << 3));
        *reinterpret_cast<ushort4*>(&tls[tidx]) = tv;
    }

    __syncthreads();   // tls + accb-zero ready

    f32x4 acc[8];
#pragma unroll
    for (int rt = 0; rt < 8; ++rt) acc[rt] = (f32x4){b2r, b2r, b2r, b2r};

    __builtin_amdgcn_s_setprio(1);
#pragma unroll
    for (int rt = 0; rt < 8; ++rt) {
        const int arow = rt * 16 + col;
        const int aswz = (arow & 7) << 3;
#pragma unroll
        for (int ks = 0; ks < 4; ++ks) {
            short8 af = *(const short8*)&tls[arow * H + ((ks * 32 + 8 * g) ^ aswz)];
            acc[rt] = __builtin_amdgcn_mfma_f32_16x16x32_bf16(af, bh[ks], acc[rt], 0, 0, 0);
            acc[rt] = __builtin_amdgcn_mfma_f32_16x16x32_bf16(af, bl[ks], acc[rt], 0, 0, 0);
        }
    }
    __builtin_amdgcn_s_setprio(0);

    // ---- run-reduce -> LDS accb (fallback to global if slot >= MAXD) ----
#pragma unroll
    for (int rt = 0; rt < 8; ++rt) {
        const int ge = ebase + rt * 16 + g * 4;
        int d0 = dst_s[ge + 0], d1 = dst_s[ge + 1];
        int d2i = dst_s[ge + 2], d3 = dst_s[ge + 3];
        float v0 = fmaxf(acc[rt][0], 0.f);
        float v1 = fmaxf(acc[rt][1], 0.f);
        float v2 = fmaxf(acc[rt][2], 0.f);
        float v3 = fmaxf(acc[rt][3], 0.f);
        float vrun = v0;
        int dcur = d0;
#define FLUSH_RUN(DD, VV)                                                          \
        if ((DD) != dcur) {                                                        \
            int sl = dcur - dfirst;                                                \
            if (sl < MAXD) atomicAdd(&accb[sl * H + nW], vrun);                    \
            else atomicAdd(&agg[(size_t)dcur * H + nW], vrun);                     \
            vrun = (VV); dcur = (DD);                                              \
        } else vrun += (VV);
        FLUSH_RUN(d1, v1)
        FLUSH_RUN(d2i, v2)
        FLUSH_RUN(d3, v3)
#undef FLUSH_RUN
        {
            int sl = dcur - dfirst;
            if (sl < MAXD) atomicAdd(&accb[sl * H + nW], vrun);
            else atomicAdd(&agg[(size_t)dcur * H + nW], vrun);
        }
    }

    __syncthreads();   // all ds adds done

    // ---- final flush: interior rows plain store, boundary rows atomicAdd ----
    {
        int span = dlast - dfirst + 1;
        if (span > MAXD) span = MAXD;
        const int colf = tid & 127;
        for (int s = tid >> 7; s < span; s += 4) {
            float v = accb[s * H + colf];
            int d = dfirst + s;
            bool bnd = (s == 0 && dprev == dfirst) || (d == dlast && dnext == dlast);
            if (bnd) atomicAdd(&agg[(size_t)d * H + colf], v);
            else agg[(size_t)d * H + colf] = v;
        }
    }
}

// ---------- node (+ optional fused proj for next layer) ----------
template <int PROJ>
__global__ __launch_bounds__(512, 4) void node_fused_kernel(
    const float* __restrict__ h, const float* __restrict__ agg,
    const ushort* __restrict__ w1h, const ushort* __restrict__ w1l,
    const ushort* __restrict__ w2h, const ushort* __restrict__ w2l,
    const float* __restrict__ b1, const float* __restrict__ b2,
    const ushort* __restrict__ pwdh, const ushort* __restrict__ pwdl,
    const ushort* __restrict__ pwsh, const ushort* __restrict__ pwsl,
    const float* __restrict__ eb1n,
    float* __restrict__ hout, ushort* __restrict__ Pdb, ushort* __restrict__ Psb)
{
    __shared__ __align__(16) ushort Abuf[128 * 64];
    __shared__ __align__(16) ushort ubuf[128 * 128];
    __shared__ __align__(16) ushort Wh[128 * 64];
    __shared__ __align__(16) ushort Wl[128 * 64];
    const int tid = threadIdx.x;
    const int nbase = blockIdx.x * 128;
    const int lane = tid & 63, wvx = tid >> 6, colL = lane & 15, g = lane >> 4;
    const int arow = wvx * 16 + colL, aswz = (arow & 7) << 3;

    f32x4 acc[8];
#pragma unroll
    for (int nt = 0; nt < 8; ++nt) {
        float bb = b1[nt * 16 + colL];
        acc[nt] = (f32x4){bb, bb, bb, bb};
    }

    const int sr = tid >> 2, skq = (tid & 3) * 16;
    const int sswz = (sr & 7) << 3;
    int sn = nbase + sr; sn = sn < NN ? sn : NN - 1;

#pragma unroll
    for (int kp = 0; kp < 4; ++kp) {
        const float* srcb = (kp < 2 ? h : agg);
        const float* src = srcb + (size_t)sn * H + (kp & 1) * 64 + skq;
#pragma unroll
        for (int j = 0; j < 2; ++j) {
            float4 a = ld4(src + 8 * j);
            float4 b = ld4(src + 8 * j + 4);
            union { ushort u[8]; int4 v; } pk;
            pk.u[0] = f2bf(a.x); pk.u[1] = f2bf(a.y); pk.u[2] = f2bf(a.z); pk.u[3] = f2bf(a.w);
            pk.u[4] = f2bf(b.x); pk.u[5] = f2bf(b.y); pk.u[6] = f2bf(b.z); pk.u[7] = f2bf(b.w);
            *reinterpret_cast<int4*>(&Abuf[sr * 64 + ((skq + 8 * j) ^ sswz)]) = pk.v;
        }
        ((int4*)Wh)[tid] = ((const int4*)(w1h + kp * 8192))[tid];
        ((int4*)Wh)[tid + 512] = ((const int4*)(w1h + kp * 8192))[tid + 512];
        ((int4*)Wl)[tid] = ((const int4*)(w1l + kp * 8192))[tid];
        ((int4*)Wl)[tid + 512] = ((const int4*)(w1l + kp * 8192))[tid + 512];
        __syncthreads();
#pragma unroll
        for (int ks = 0; ks < 2; ++ks) {
            int kk0 = ks * 32;
            short8 af = *(const short8*)&Abuf[arow * 64 + ((kk0 + 8 * g) ^ aswz)];
#pragma unroll
            for (int nt = 0; nt < 8; ++nt) {
                int brow = nt * 16 + colL;
                int bidx = brow * 64 + ((kk0 + 8 * g) ^ ((brow & 7) << 3));
                short8 bh = *(const short8*)&Wh[bidx];
                short8 bl = *(const short8*)&Wl[bidx];
                acc[nt] = __builtin_amdgcn_mfma_f32_16x16x32_bf16(af, bh, acc[nt], 0, 0, 0);
                acc[nt] = __builtin_amdgcn_mfma_f32_16x16x32_bf16(af, bl, acc[nt], 0, 0, 0);
            }
        }
        __syncthreads();
    }

    const int rowb = wvx * 16 + g * 4;
#pragma unroll
    for (int r = 0; r < 4; ++r) {
        int row = rowb + r;
        int rs = (row & 7) << 3;
#pragma unroll
        for (int nt = 0; nt < 8; ++nt) {
            ubuf[row * 128 + ((nt * 16 + colL) ^ rs)] = f2bf(fmaxf(acc[nt][r], 0.f));
        }
    }
    __syncthreads();

    f32x4 acc2[8];
#pragma unroll
    for (int nt = 0; nt < 8; ++nt) {
        float bb = b2[nt * 16 + colL];
        acc2[nt] = (f32x4){bb, bb, bb, bb};
    }
#pragma unroll
    for (int kp2 = 0; kp2 < 2; ++kp2) {
        ((int4*)Wh)[tid] = ((const int4*)(w2h + kp2 * 8192))[tid];
        ((int4*)Wh)[tid + 512] = ((const int4*)(w2h + kp2 * 8192))[tid + 512];
        ((int4*)Wl)[tid] = ((const int4*)(w2l + kp2 * 8192))[tid];
        ((int4*)Wl)[tid + 512] = ((const int4*)(w2l + kp2 * 8192))[tid + 512];
        __syncthreads();
#pragma unroll
        for (int ks = 0; ks < 2; ++ks) {
            int kk0 = ks * 32;
            short8 af = *(const short8*)&ubuf[arow * 128 + ((kp2 * 64 + kk0 + 8 * g) ^ aswz)];
#pragma unroll
            for (int nt = 0; nt < 8; ++nt) {
                int brow = nt * 16 + colL;
                int bidx = brow * 64 + ((kk0 + 8 * g) ^ ((brow & 7) << 3));
                short8 bh = *(const short8*)&Wh[bidx];
                short8 bl = *(const short8*)&Wl[bidx];
                acc2[nt] = __builtin_amdgcn_mfma_f32_16x16x32_bf16(af, bh, acc2[nt], 0, 0, 0);
                acc2[nt] = __builtin_amdgcn_mfma_f32_16x16x32_bf16(af, bl, acc2[nt], 0, 0, 0);
            }
        }
        __syncthreads();
    }

#pragma unroll
    for (int r = 0; r < 4; ++r) {
        int n = nbase + rowb + r;
        if (n < NN) {
#pragma unroll
            for (int nt = 0; nt < 8; ++nt)
                hout[(size_t)n * H + nt * 16 + colL] = acc2[nt][r];
        }
    }

    if (PROJ) {
#pragma unroll
        for (int r = 0; r < 4; ++r) {
            int row = rowb + r;
            int rs = (row & 7) << 3;
#pragma unroll
            for (int nt = 0; nt < 8; ++nt) {
                ubuf[row * 128 + ((nt * 16 + colL) ^ rs)] = f2bf(acc2[nt][r]);
            }
        }
        __syncthreads();

        f32x4 accd[8], accs[8];
#pragma unroll
        for (int nt = 0; nt < 8; ++nt) { accd[nt] = (f32x4){0, 0, 0, 0}; accs[nt] = (f32x4){0, 0, 0, 0}; }

        PROJ_ROUND(ubuf, pwdh, pwdl, 0, accd)
        PROJ_ROUND(ubuf, pwdh + 8192, pwdl + 8192, 64, accd)
        PROJ_ROUND(ubuf, pwsh, pwsl, 0, accs)
        PROJ_ROUND(ubuf, pwsh + 8192, pwsl + 8192, 64, accs)

        float b1r[8];
#pragma unroll
        for (int nt = 0; nt < 8; ++nt) b1r[nt] = eb1n[nt * 16 + colL];
#pragma unroll
        for (int r = 0; r < 4; ++r) {
            int n = nbase + rowb + r;
            if (n < NN) {
#pragma unroll
                for (int nt = 0; nt < 8; ++nt) {
                    Pdb[(size_t)n * H + nt * 16 + colL] = f2bf(accd[nt][r] + b1r[nt]);
                    Psb[(size_t)n * H + nt * 16 + colL] = f2bf(accs[nt][r]);
                }
            }
        }
    }
}

__global__ __launch_bounds__(256) void pool_kernel(const float* __restrict__ h,
    const int* __restrict__ batch, float* __restrict__ ssum,
    unsigned int* __restrict__ smaxk, float* __restrict__ cnt)
{
    const int tid = threadIdx.x, j = tid & 127, half = tid >> 7;
    const int nbase = blockIdx.x * 64;
    int cur = -1, rc = 0;
    float s = 0.f, mx = 0.f;
    for (int i = 0; i < 32; ++i) {
        int n = nbase + 2 * i + half;
        if (n >= NN) break;
        int g = batch[n];
        float v = h[(size_t)n * H + j];
        if (g != cur) {
            if (cur >= 0) {
                atomicAdd(&ssum[cur * H + j], s);
                atomicMax(&smaxk[cur * H + j], fkey(mx));
                if (j == 0) atomicAdd(&cnt[cur], (float)rc);
            }
            cur = g; s = v; mx = v; rc = 1;
        } else { s += v; mx = fmaxf(mx, v); rc++; }
    }
    if (cur >= 0) {
        atomicAdd(&ssum[cur * H + j], s);
        atomicMax(&smaxk[cur * H + j], fkey(mx));
        if (j == 0) atomicAdd(&cnt[cur], (float)rc);
    }
}

__global__ __launch_bounds__(128) void readout_kernel(const float* __restrict__ ssum,
    const unsigned int* __restrict__ smaxk, const float* __restrict__ cnt,
    const float* __restrict__ rW1, const float* __restrict__ rb1,
    const float* __restrict__ rW2, const float* __restrict__ rb2,
    const float* __restrict__ rW3, const float* __restrict__ rb3,
    float* __restrict__ out)
{
    __shared__ float p[384], h1[128], h2[64];
    const int g = blockIdx.x, j = threadIdx.x;
    float c = fmaxf(cnt[g], 1.0f);
    float sv = ssum[g * H + j];
    p[j] = sv / c;
    p[128 + j] = funkey(smaxk[g * H + j]);
    p[256 + j] = sv;
    __syncthreads();
    float a = rb1[j];
    for (int k = 0; k < 384; ++k) a = fmaf(p[k], rW1[k * H + j], a);
    h1[j] = fmaxf(a, 0.f);
    __syncthreads();
    if (j < 64) {
        float a2 = rb2[j];
        for (int k = 0; k < 128; ++k) a2 = fmaf(h1[k], rW2[k * 64 + j], a2);
        h2[j] = fmaxf(a2, 0.f);
    }
    __syncthreads();
    if (j < 64) {
        float t = h2[j] * rW3[j];
        for (int off = 32; off; off >>= 1) t += __shfl_down(t, off);
        if (j == 0) {
            float z = t + rb3[0];
            out[g] = z > 20.f ? z : log1pf(expf(z));
        }
    }
}

extern "C" void kernel_launch(void* const* d_in, const int* in_sizes, int n_in,
                              void* d_out, int out_size, void* d_ws, size_t ws_size,
                              hipStream_t stream)
{
    const float* x    = (const float*)d_in[0];
    const float* pos  = (const float*)d_in[1];
    const float* ea   = (const float*)d_in[2];
    const int*   ei   = (const int*)d_in[3];
    const int*   batch= (const int*)d_in[4];
    const float* encW = (const float*)d_in[5];
    const float* encb = (const float*)d_in[6];
    const float* eW1  = (const float*)d_in[7];
    const float* eb1  = (const float*)d_in[8];
    const float* eW2  = (const float*)d_in[9];
    const float* eb2  = (const float*)d_in[10];
    const float* nW1  = (const float*)d_in[11];
    const float* nb1  = (const float*)d_in[12];
    const float* nW2  = (const float*)d_in[13];
    const float* nb2  = (const float*)d_in[14];
    const float* rW1  = (const float*)d_in[15];
    const float* rb1  = (const float*)d_in[16];
    const float* rW2  = (const float*)d_in[17];
    const float* rb2  = (const float*)d_in[18];
    const float* rW3  = (const float*)d_in[19];
    const float* rb3  = (const float*)d_in[20];

    char* w = (char*)d_ws;
    size_t o = 0;
    auto alloc = [&](size_t bytes) -> char* {
        char* p = w + o; o += (bytes + 255) / 256 * 256; return p;
    };
    float* hA   = (float*)alloc((size_t)NN * H * 4);
    float* hB   = (float*)alloc((size_t)NN * H * 4);
    ushort* Pdb = (ushort*)alloc((size_t)NN * H * 2);
    ushort* Psb = (ushort*)alloc((size_t)NN * H * 2);
    float* agg  = (float*)alloc((size_t)NN * H * 4);
    float* d2   = (float*)alloc((size_t)NE * 4);
    float* ssum = (float*)alloc((size_t)NG * H * 4);
    unsigned int* smaxk = (unsigned int*)alloc((size_t)NG * H * 4);
    float* cnt  = (float*)alloc((size_t)NG * 4);
    int*   deg    = (int*)alloc((size_t)NN * 4);
    int*   cursor = (int*)alloc((size_t)NN * 4);
    int*   src_s  = (int*)alloc((size_t)NE * 4);
    int*   dst_s  = (int*)alloc((size_t)NE * 4);
    float* ea_s   = (float*)alloc((size_t)NE * DEA * 4);
    float* d2_s   = (float*)alloc((size_t)NE * 4);
    ushort* w2hi  = (ushort*)alloc((size_t)NL * H * H * 2);
    ushort* w2lo  = (ushort*)alloc((size_t)NL * H * H * 2);
    ushort* nw1hi = (ushort*)alloc((size_t)NL * 256 * H * 2);
    ushort* nw1lo = (ushort*)alloc((size_t)NL * 256 * H * 2);
    ushort* nw2hi = (ushort*)alloc((size_t)NL * H * H * 2);
    ushort* nw2lo = (ushort*)alloc((size_t)NL * H * H * 2);
    ushort* w1dhi = (ushort*)alloc((size_t)NL * H * H * 2);
    ushort* w1dlo = (ushort*)alloc((size_t)NL * H * H * 2);
    ushort* w1shi = (ushort*)alloc((size_t)NL * H * H * 2);
    ushort* w1slo = (ushort*)alloc((size_t)NL * H * H * 2);
    (void)ws_size; (void)in_sizes; (void)n_in; (void)out_size;

    const int NB = (NN + 63) / 64;
    const int NBM = (NN + 127) / 128;
    const int EB = (NE + 255) / 256;

    (void)hipMemsetAsync(deg, 0, (size_t)NN * 4, stream);
    dist2_kernel<<<EB, 256, 0, stream>>>(pos, ei, d2);
    hist_kernel<<<EB, 256, 0, stream>>>(ei, deg);
    scan_kernel<<<1, 1024, 0, stream>>>(deg, cursor);
    scatter_kernel<<<EB, 256, 0, stream>>>(ei, ea, d2, cursor, src_s, dst_s, ea_s, d2_s);

    wprep_kernel<<<dim3(64, NL), 256, 0, stream>>>(eW2, w2hi, w2lo, H, H * H, H * H);
    wprep_kernel<<<dim3(128, NL), 256, 0, stream>>>(nW1, nw1hi, nw1lo, 256, 256 * H, 256 * H);
    wprep_kernel<<<dim3(64, NL), 256, 0, stream>>>(nW2, nw2hi, nw2lo, H, H * H, H * H);
    wprep_kernel<<<dim3(64, NL), 256, 0, stream>>>(eW1, w1dhi, w1dlo, H, 273 * H, H * H);
    wprep_kernel<<<dim3(64, NL), 256, 0, stream>>>(eW1 + 128 * H, w1shi, w1slo, H, 273 * H, H * H);

    encoder_kernel<<<NB, 256, 0, stream>>>(x, encW, encb, hA);

    // layer-0 proj
    proj_mfma_kernel<<<NBM, 512, 0, stream>>>(hA,
        w1dhi, w1dlo, w1shi, w1slo, eb1, Pdb, Psb);

    float* hcur = hA;
    float* hnext = hB;
    for (int l = 0; l < NL; ++l) {
        (void)hipMemsetAsync(agg, 0, (size_t)NN * H * 4, stream);
        edge_mfma_kernel<<<NE / EPB, 512, 0, stream>>>(Pdb, Psb, ea_s, d2_s, src_s, dst_s,
            eW1 + (size_t)l * 273 * H, w2hi + (size_t)l * H * H, w2lo + (size_t)l * H * H,
            eb2 + l * H, agg);
        if (l < NL - 1) {
            int ln = l + 1;
            node_fused_kernel<1><<<NBM, 512, 0, stream>>>(hcur, agg,
                nw1hi + (size_t)l * 256 * H, nw1lo + (size_t)l * 256 * H,
                nw2hi + (size_t)l * H * H, nw2lo + (size_t)l * H * H,
                nb1 + l * H, nb2 + l * H,
                w1dhi + (size_t)ln * H * H, w1dlo + (size_t)ln * H * H,
                w1shi + (size_t)ln * H * H, w1slo + (size_t)ln * H * H,
                eb1 + ln * H, hnext, Pdb, Psb);
        } else {
            node_fused_kernel<0><<<NBM, 512, 0, stream>>>(hcur, agg,
                nw1hi + (size_t)l * 256 * H, nw1lo + (size_t)l * 256 * H,
                nw2hi + (size_t)l * H * H, nw2lo + (size_t)l * H * H,
                nb1 + l * H, nb2 + l * H,
                (const ushort*)nullptr, (const ushort*)nullptr,
                (const ushort*)nullptr, (const ushort*)nullptr,
                (const float*)nullptr, hnext, Pdb, Psb);
        }
        float* tmp = hcur; hcur = hnext; hnext = tmp;
    }

    (void)hipMemsetAsync(ssum, 0, (size_t)NG * H * 4, stream);
    (void)hipMemsetAsync(smaxk, 0, (size_t)NG * H * 4, stream);
    (void)hipMemsetAsync(cnt, 0, (size_t)NG * 4, stream);
    pool_kernel<<<NB, 256, 0, stream>>>(hcur, batch, ssum, smaxk, cnt);
    readout_kernel<<<NG, 128, 0, stream>>>(ssum, smaxk, cnt,
        rW1, rb1, rW2, rb2, rW3, rb3, (float*)d_out);
}

// Round 17
// 1362.052 us; speedup vs baseline: 1.0698x; 1.0698x over previous
//
#include <hip/hip_runtime.h>
#include <math.h>

#define NN 50000
#define NE 800000
#define NG 64
#define DIN 64
#define DEA 16
#define H 128
#define NL 4
#define EPB 128   // edges per block in edge_mfma_kernel
#define MAXD 16   // LDS dst-slot rows (8KB -> 40KB total)

typedef __attribute__((ext_vector_type(8))) short short8;
typedef __attribute__((ext_vector_type(4))) float f32x4;

__device__ __forceinline__ float4 ld4(const float* p) { return *reinterpret_cast<const float4*>(p); }
__device__ __forceinline__ void st4(float* p, float4 v) { *reinterpret_cast<float4*>(p) = v; }
__device__ __forceinline__ void fma4(float4& a, float s, float4 w) {
    a.x = fmaf(s, w.x, a.x); a.y = fmaf(s, w.y, a.y);
    a.z = fmaf(s, w.z, a.z); a.w = fmaf(s, w.w, a.w);
}
__device__ __forceinline__ float4 f4add(float4 a, float4 b) {
    return make_float4(a.x + b.x, a.y + b.y, a.z + b.z, a.w + b.w);
}
__device__ __forceinline__ float4 relu4(float4 a) {
    return make_float4(fmaxf(a.x, 0.f), fmaxf(a.y, 0.f), fmaxf(a.z, 0.f), fmaxf(a.w, 0.f));
}
__device__ __forceinline__ unsigned fkey(float f) {
    unsigned b = __float_as_uint(f);
    return (b & 0x80000000u) ? ~b : (b | 0x80000000u);
}
__device__ __forceinline__ float funkey(unsigned k) {
    unsigned b = (k & 0x80000000u) ? (k ^ 0x80000000u) : ~k;
    return __uint_as_float(b);
}
__device__ __forceinline__ ushort f2bf(float f) {
    unsigned u = __float_as_uint(f);
    return (ushort)((u + 0x7fffu + ((u >> 16) & 1u)) >> 16);
}
__device__ __forceinline__ float bf2f(ushort b) {
    return __uint_as_float(((unsigned)b) << 16);
}

// h = relu(x @ encW + encb), x:[NN,64], W:[64,128]
__global__ __launch_bounds__(256) void encoder_kernel(const float* __restrict__ x,
    const float* __restrict__ W, const float* __restrict__ b, float* __restrict__ h)
{
    const int tid = threadIdx.x, q = tid & 31, no = tid >> 5;
    const int nbase = blockIdx.x * 64;
    float4 bv = ld4(b + 4 * q);
    float4 acc[8];
#pragma unroll
    for (int i = 0; i < 8; ++i) acc[i] = bv;
    for (int k4 = 0; k4 < 16; ++k4) {
        const float* wp = W + (4 * k4) * H + 4 * q;
        float4 w0 = ld4(wp), w1 = ld4(wp + H), w2 = ld4(wp + 2 * H), w3 = ld4(wp + 3 * H);
#pragma unroll
        for (int i = 0; i < 8; ++i) {
            int n = nbase + no * 8 + i; n = n < NN ? n : NN - 1;
            float4 a = ld4(x + n * DIN + 4 * k4);
            fma4(acc[i], a.x, w0); fma4(acc[i], a.y, w1);
            fma4(acc[i], a.z, w2); fma4(acc[i], a.w, w3);
        }
    }
#pragma unroll
    for (int i = 0; i < 8; ++i) {
        int n = nbase + no * 8 + i;
        if (n < NN) st4(h + n * H + 4 * q, relu4(acc[i]));
    }
}

__global__ __launch_bounds__(256) void dist2_kernel(const float* __restrict__ pos,
    const int* __restrict__ ei, float* __restrict__ d2)
{
    int e = blockIdx.x * 256 + threadIdx.x;
    if (e >= NE) return;
    int s = ei[e], d = ei[NE + e];
    float dx = pos[s * 3 + 0] - pos[d * 3 + 0];
    float dy = pos[s * 3 + 1] - pos[d * 3 + 1];
    float dz = pos[s * 3 + 2] - pos[d * 3 + 2];
    d2[e] = dx * dx + dy * dy + dz * dz;
}

// ---------- counting sort of edges by dst ----------
__global__ __launch_bounds__(256) void hist_kernel(const int* __restrict__ ei, int* __restrict__ deg)
{
    int e = blockIdx.x * 256 + threadIdx.x;
    if (e < NE) atomicAdd(&deg[ei[NE + e]], 1);
}

__global__ __launch_bounds__(1024) void scan_kernel(const int* __restrict__ deg, int* __restrict__ cursor)
{
    __shared__ int tot[1024];
    const int t = threadIdx.x;
    const int CH = (NN + 1023) / 1024;
    const int base = t * CH;
    int s = 0;
    for (int i = 0; i < CH; ++i) {
        int idx = base + i;
        if (idx < NN) s += deg[idx];
    }
    tot[t] = s;
    __syncthreads();
    for (int off = 1; off < 1024; off <<= 1) {
        int v = (t >= off) ? tot[t - off] : 0;
        __syncthreads();
        tot[t] += v;
        __syncthreads();
    }
    int run = (t == 0) ? 0 : tot[t - 1];
    for (int i = 0; i < CH; ++i) {
        int idx = base + i;
        if (idx < NN) { cursor[idx] = run; run += deg[idx]; }
    }
}

__global__ __launch_bounds__(256) void scatter_kernel(const int* __restrict__ ei,
    const float* __restrict__ ea, const float* __restrict__ d2, int* __restrict__ cursor,
    int* __restrict__ src_s, int* __restrict__ dst_s,
    float* __restrict__ ea_s, float* __restrict__ d2_s)
{
    int e = blockIdx.x * 256 + threadIdx.x;
    if (e >= NE) return;
    int s = ei[e], d = ei[NE + e];
    int pos = atomicAdd(&cursor[d], 1);
    src_s[pos] = s; dst_s[pos] = d; d2_s[pos] = d2[e];
    const float4* ev = reinterpret_cast<const float4*>(ea + (size_t)e * DEA);
    float4* ov = reinterpret_cast<float4*>(ea_s + (size_t)pos * DEA);
    ov[0] = ev[0]; ov[1] = ev[1]; ov[2] = ev[2]; ov[3] = ev[3];
}

// ---------- generic W [K x 128] -> split bf16 (hi+lo), transposed [n][k], k-panel-64 swizzled ----------
__global__ __launch_bounds__(256) void wprep_kernel(const float* __restrict__ W,
    ushort* __restrict__ hi, ushort* __restrict__ lo,
    int K, int in_lstride, int out_lstride)
{
    int l = blockIdx.y;
    const float* Wb = W + (size_t)l * in_lstride;
    ushort* hg = hi + (size_t)l * out_lstride;
    ushort* lg = lo + (size_t)l * out_lstride;
    int total = K * 128;
    for (int idx = blockIdx.x * 256 + threadIdx.x; idx < total; idx += gridDim.x * 256) {
        int k = idx >> 7, n = idx & 127;
        float wv = Wb[idx];
        ushort hb = f2bf(wv);
        float rem = wv - bf2f(hb);
        ushort lb = f2bf(rem);
        int panel = k >> 6, kk = k & 63;
        int pos = panel * 8192 + (n << 6) + (kk ^ ((n & 7) << 3));
        hg[pos] = hb; lg[pos] = lb;
    }
}

// ---------- proj (layer 0 only): Pdb = bf16(h@W1d + b1), Psb = bf16(h@W1s) ----------
__global__ __launch_bounds__(512, 4) void proj_mfma_kernel(const float* __restrict__ h,
    const ushort* __restrict__ wdh, const ushort* __restrict__ wdl,
    const ushort* __restrict__ wsh, const ushort* __restrict__ wsl,
    const float* __restrict__ b1,
    ushort* __restrict__ Pdb, ushort* __restrict__ Psb)
{
    __shared__ __align__(16) ushort Afull[128 * 128];
    __shared__ __align__(16) ushort Wh[128 * 64];
    __shared__ __align__(16) ushort Wl[128 * 64];
    const int tid = threadIdx.x;
    const int nbase = blockIdx.x * 128;

    {
        int r = tid >> 2, kq = (tid & 3) * 32;
        int n = nbase + r; n = n < NN ? n : NN - 1;
        const float* src = h + (size_t)n * H + kq;
        int swz = (r & 7) << 3;
#pragma unroll
        for (int j = 0; j < 4; ++j) {
            float4 a = ld4(src + 8 * j);
            float4 b = ld4(src + 8 * j + 4);
            union { ushort u[8]; int4 v; } pk;
            pk.u[0] = f2bf(a.x); pk.u[1] = f2bf(a.y); pk.u[2] = f2bf(a.z); pk.u[3] = f2bf(a.w);
            pk.u[4] = f2bf(b.x); pk.u[5] = f2bf(b.y); pk.u[6] = f2bf(b.z); pk.u[7] = f2bf(b.w);
            *reinterpret_cast<int4*>(&Afull[r * 128 + ((kq + 8 * j) ^ swz)]) = pk.v;
        }
    }

    const int lane = tid & 63, wvx = tid >> 6, colL = lane & 15, g = lane >> 4;
    const int arow = wvx * 16 + colL, aswz = (arow & 7) << 3;
    f32x4 accd[8], accs[8];
#pragma unroll
    for (int nt = 0; nt < 8; ++nt) { accd[nt] = (f32x4){0, 0, 0, 0}; accs[nt] = (f32x4){0, 0, 0, 0}; }

#define PROJ_ROUND(ABUF, HSRC, LSRC, KOFF, ACC)                                         \
    {                                                                                   \
        ((int4*)Wh)[tid] = ((const int4*)(HSRC))[tid];                                  \
        ((int4*)Wh)[tid + 512] = ((const int4*)(HSRC))[tid + 512];                      \
        ((int4*)Wl)[tid] = ((const int4*)(LSRC))[tid];                                  \
        ((int4*)Wl)[tid + 512] = ((const int4*)(LSRC))[tid + 512];                      \
        __syncthreads();                                                                \
        _Pragma("unroll")                                                               \
        for (int ks = 0; ks < 2; ++ks) {                                                \
            int kk0 = ks * 32;                                                          \
            short8 af = *(const short8*)&ABUF[arow * 128 + (((KOFF) + kk0 + 8 * g) ^ aswz)]; \
            _Pragma("unroll")                                                           \
            for (int nt = 0; nt < 8; ++nt) {                                            \
                int brow = nt * 16 + colL;                                              \
                int bidx = brow * 64 + ((kk0 + 8 * g) ^ ((brow & 7) << 3));             \
                short8 bh = *(const short8*)&Wh[bidx];                                  \
                short8 bl = *(const short8*)&Wl[bidx];                                  \
                ACC[nt] = __builtin_amdgcn_mfma_f32_16x16x32_bf16(af, bh, ACC[nt], 0, 0, 0); \
                ACC[nt] = __builtin_amdgcn_mfma_f32_16x16x32_bf16(af, bl, ACC[nt], 0, 0, 0); \
            }                                                                           \
        }                                                                               \
        __syncthreads();                                                                \
    }

    PROJ_ROUND(Afull, wdh, wdl, 0, accd)
    PROJ_ROUND(Afull, wdh + 8192, wdl + 8192, 64, accd)
    PROJ_ROUND(Afull, wsh, wsl, 0, accs)
    PROJ_ROUND(Afull, wsh + 8192, wsl + 8192, 64, accs)

    float b1r[8];
#pragma unroll
    for (int nt = 0; nt < 8; ++nt) b1r[nt] = b1[nt * 16 + colL];

    const int rowb = wvx * 16 + g * 4;
#pragma unroll
    for (int r = 0; r < 4; ++r) {
        int n = nbase + rowb + r;
        if (n < NN) {
#pragma unroll
            for (int nt = 0; nt < 8; ++nt) {
                Pdb[(size_t)n * H + nt * 16 + colL] = f2bf(accd[nt][r] + b1r[nt]);
                Psb[(size_t)n * H + nt * 16 + colL] = f2bf(accs[nt][r]);
            }
        }
    }
}

// dst-sorted edges, 128 edges/block, 8 waves. XCD-chunked bijective block swizzle.
// stage1: t = relu(Pdb[dst]+Psb[src]+d2*wd+ea@Wea) -> bf16 swizzled LDS
// stage2: wave owns 16 output cols, W2 col-slice in registers (loaded after stage 1)
// reduce: run-reduce -> LDS accb[dst-dfirst] (MAXD=16 slots; fallback global atomic) ->
//         interior rows plain store, boundary rows atomicAdd.
__global__ __launch_bounds__(512, 4) void edge_mfma_kernel(
    const ushort* __restrict__ Pdb, const ushort* __restrict__ Psb,
    const float* __restrict__ ea_s, const float* __restrict__ d2_s,
    const int* __restrict__ src_s, const int* __restrict__ dst_s,
    const float* __restrict__ W1,
    const ushort* __restrict__ w2hiL, const ushort* __restrict__ w2loL,
    const float* __restrict__ b2, float* __restrict__ agg)
{
    __shared__ __align__(16) ushort tls[EPB * H];   // 32KB
    __shared__ __align__(16) float accb[MAXD * H];  // 8KB

    // bijective XCD chunked swizzle (m204): nwg = NE/EPB = 6250, 8 XCDs
    const int NWG = NE / EPB, QQ = NWG / 8, RR = NWG % 8;
    int orig = blockIdx.x;
    int xcd = orig & 7, ixc = orig >> 3;
    int bswz = (xcd < RR ? xcd * (QQ + 1) : RR * (QQ + 1) + (xcd - RR) * QQ) + ixc;

    const int tid = threadIdx.x, q = tid & 31, eo = tid >> 5;
    const int ebase = bswz * EPB;
    const int lane = tid & 63, wv = tid >> 6;
    const int col = lane & 15, g = lane >> 4;

    // zero accb (MAXD*H = 2048 floats, 512 threads x 4)
    st4(&accb[tid * 4], make_float4(0.f, 0.f, 0.f, 0.f));

    // block dst range + boundary info (uniform scalar loads)
    const int dfirst = dst_s[ebase];
    const int dlast  = dst_s[ebase + EPB - 1];
    const int dprev  = (ebase > 0) ? dst_s[ebase - 1] : -1;
    const int dnext  = (ebase + EPB < NE) ? dst_s[ebase + EPB] : -1;

    // ---- stage 1: edge MLP layer-1 (fp32, bf16 gathers) ----
    const float* Wea = W1 + 256 * H;
    const float* wdv = W1 + 272 * H;
    float4 wdq = ld4(wdv + 4 * q);

    int srcs[8], dsts8[8];
    float d2v[8];
#pragma unroll
    for (int i = 0; i < 8; ++i) {
        int j = ebase + eo * 8 + i;
        srcs[i] = src_s[j]; dsts8[i] = dst_s[j]; d2v[i] = d2_s[j];
    }
    float4 acc1[8];
#pragma unroll
    for (int i = 0; i < 8; ++i) {
        ushort4 pd4 = *reinterpret_cast<const ushort4*>(&Pdb[(size_t)dsts8[i] * H + 4 * q]);
        ushort4 ps4 = *reinterpret_cast<const ushort4*>(&Psb[(size_t)srcs[i] * H + 4 * q]);
        float4 a;
        a.x = bf2f(pd4.x) + bf2f(ps4.x);
        a.y = bf2f(pd4.y) + bf2f(ps4.y);
        a.z = bf2f(pd4.z) + bf2f(ps4.z);
        a.w = bf2f(pd4.w) + bf2f(ps4.w);
        fma4(a, d2v[i], wdq);
        acc1[i] = a;
    }
#pragma unroll
    for (int k4 = 0; k4 < 4; ++k4) {
        float4 w0 = ld4(Wea + (4 * k4 + 0) * H + 4 * q);
        float4 w1 = ld4(Wea + (4 * k4 + 1) * H + 4 * q);
        float4 w2 = ld4(Wea + (4 * k4 + 2) * H + 4 * q);
        float4 w3 = ld4(Wea + (4 * k4 + 3) * H + 4 * q);
#pragma unroll
        for (int i = 0; i < 8; ++i) {
            int j = ebase + eo * 8 + i;
            float4 av = ld4(ea_s + (size_t)j * DEA + 4 * k4);
            fma4(acc1[i], av.x, w0); fma4(acc1[i], av.y, w1);
            fma4(acc1[i], av.z, w2); fma4(acc1[i], av.w, w3);
        }
    }
#pragma unroll
    for (int i = 0; i < 8; ++i) {
        int el = eo * 8 + i;
        ushort4 tv;
        tv.x = f2bf(fmaxf(acc1[i].x, 0.f)); tv.y = f2bf(fmaxf(acc1[i].y, 0.f));
        tv.z = f2bf(fmaxf(acc1[i].z, 0.f)); tv.w = f2bf(fmaxf(acc1[i].w, 0.f));
        int tidx = el * H + ((4 * q) ^ ((el & 7) << 3));
        *reinterpret_cast<ushort4*>(&tls[tidx]) = tv;
    }

    // ---- wave's W2^T col-slice (hi+lo) into registers ----
    const int nW = wv * 16 + col;
    const int nswz = (nW & 7) << 3;
    short8 bh[4], bl[4];
#pragma unroll
    for (int ks = 0; ks < 4; ++ks) {
        int kkg = ks * 32 + 8 * g;
        int panel = kkg >> 6, kk = kkg & 63;
        int pos = panel * 8192 + nW * 64 + (kk ^ nswz);
        bh[ks] = *reinterpret_cast<const short8*>(&w2hiL[pos]);
        bl[ks] = *reinterpret_cast<const short8*>(&w2loL[pos]);
    }
    float b2r = b2[nW];

    __syncthreads();   // tls + accb-zero ready

    f32x4 acc[8];
#pragma unroll
    for (int rt = 0; rt < 8; ++rt) acc[rt] = (f32x4){b2r, b2r, b2r, b2r};

    __builtin_amdgcn_s_setprio(1);
#pragma unroll
    for (int rt = 0; rt < 8; ++rt) {
        const int arow = rt * 16 + col;
        const int aswz = (arow & 7) << 3;
#pragma unroll
        for (int ks = 0; ks < 4; ++ks) {
            short8 af = *(const short8*)&tls[arow * H + ((ks * 32 + 8 * g) ^ aswz)];
            acc[rt] = __builtin_amdgcn_mfma_f32_16x16x32_bf16(af, bh[ks], acc[rt], 0, 0, 0);
            acc[rt] = __builtin_amdgcn_mfma_f32_16x16x32_bf16(af, bl[ks], acc[rt], 0, 0, 0);
        }
    }
    __builtin_amdgcn_s_setprio(0);

    // ---- run-reduce -> LDS accb (fallback to global if slot >= MAXD) ----
#pragma unroll
    for (int rt = 0; rt < 8; ++rt) {
        const int ge = ebase + rt * 16 + g * 4;
        int d0 = dst_s[ge + 0], d1 = dst_s[ge + 1];
        int d2i = dst_s[ge + 2], d3 = dst_s[ge + 3];
        float v0 = fmaxf(acc[rt][0], 0.f);
        float v1 = fmaxf(acc[rt][1], 0.f);
        float v2 = fmaxf(acc[rt][2], 0.f);
        float v3 = fmaxf(acc[rt][3], 0.f);
        float vrun = v0;
        int dcur = d0;
#define FLUSH_RUN(DD, VV)                                                          \
        if ((DD) != dcur) {                                                        \
            int sl = dcur - dfirst;                                                \
            if (sl < MAXD) atomicAdd(&accb[sl * H + nW], vrun);                    \
            else atomicAdd(&agg[(size_t)dcur * H + nW], vrun);                     \
            vrun = (VV); dcur = (DD);                                              \
        } else vrun += (VV);
        FLUSH_RUN(d1, v1)
        FLUSH_RUN(d2i, v2)
        FLUSH_RUN(d3, v3)
#undef FLUSH_RUN
        {
            int sl = dcur - dfirst;
            if (sl < MAXD) atomicAdd(&accb[sl * H + nW], vrun);
            else atomicAdd(&agg[(size_t)dcur * H + nW], vrun);
        }
    }

    __syncthreads();   // all ds adds done

    // ---- final flush: interior rows plain store, boundary rows atomicAdd ----
    {
        int span = dlast - dfirst + 1;
        if (span > MAXD) span = MAXD;
        const int colf = tid & 127;
        for (int s = tid >> 7; s < span; s += 4) {
            float v = accb[s * H + colf];
            int d = dfirst + s;
            bool bnd = (s == 0 && dprev == dfirst) || (d == dlast && dnext == dlast);
            if (bnd) atomicAdd(&agg[(size_t)d * H + colf], v);
            else agg[(size_t)d * H + colf] = v;
        }
    }
}

// ---------- node (+ optional fused proj for next layer) ----------
template <int PROJ>
__global__ __launch_bounds__(512, 4) void node_fused_kernel(
    const float* __restrict__ h, const float* __restrict__ agg,
    const ushort* __restrict__ w1h, const ushort* __restrict__ w1l,
    const ushort* __restrict__ w2h, const ushort* __restrict__ w2l,
    const float* __restrict__ b1, const float* __restrict__ b2,
    const ushort* __restrict__ pwdh, const ushort* __restrict__ pwdl,
    const ushort* __restrict__ pwsh, const ushort* __restrict__ pwsl,
    const float* __restrict__ eb1n,
    float* __restrict__ hout, ushort* __restrict__ Pdb, ushort* __restrict__ Psb)
{
    __shared__ __align__(16) ushort Abuf[128 * 64];
    __shared__ __align__(16) ushort ubuf[128 * 128];
    __shared__ __align__(16) ushort Wh[128 * 64];
    __shared__ __align__(16) ushort Wl[128 * 64];
    const int tid = threadIdx.x;
    const int nbase = blockIdx.x * 128;
    const int lane = tid & 63, wvx = tid >> 6, colL = lane & 15, g = lane >> 4;
    const int arow = wvx * 16 + colL, aswz = (arow & 7) << 3;

    f32x4 acc[8];
#pragma unroll
    for (int nt = 0; nt < 8; ++nt) {
        float bb = b1[nt * 16 + colL];
        acc[nt] = (f32x4){bb, bb, bb, bb};
    }

    const int sr = tid >> 2, skq = (tid & 3) * 16;
    const int sswz = (sr & 7) << 3;
    int sn = nbase + sr; sn = sn < NN ? sn : NN - 1;

#pragma unroll
    for (int kp = 0; kp < 4; ++kp) {
        const float* srcb = (kp < 2 ? h : agg);
        const float* src = srcb + (size_t)sn * H + (kp & 1) * 64 + skq;
#pragma unroll
        for (int j = 0; j < 2; ++j) {
            float4 a = ld4(src + 8 * j);
            float4 b = ld4(src + 8 * j + 4);
            union { ushort u[8]; int4 v; } pk;
            pk.u[0] = f2bf(a.x); pk.u[1] = f2bf(a.y); pk.u[2] = f2bf(a.z); pk.u[3] = f2bf(a.w);
            pk.u[4] = f2bf(b.x); pk.u[5] = f2bf(b.y); pk.u[6] = f2bf(b.z); pk.u[7] = f2bf(b.w);
            *reinterpret_cast<int4*>(&Abuf[sr * 64 + ((skq + 8 * j) ^ sswz)]) = pk.v;
        }
        ((int4*)Wh)[tid] = ((const int4*)(w1h + kp * 8192))[tid];
        ((int4*)Wh)[tid + 512] = ((const int4*)(w1h + kp * 8192))[tid + 512];
        ((int4*)Wl)[tid] = ((const int4*)(w1l + kp * 8192))[tid];
        ((int4*)Wl)[tid + 512] = ((const int4*)(w1l + kp * 8192))[tid + 512];
        __syncthreads();
#pragma unroll
        for (int ks = 0; ks < 2; ++ks) {
            int kk0 = ks * 32;
            short8 af = *(const short8*)&Abuf[arow * 64 + ((kk0 + 8 * g) ^ aswz)];
#pragma unroll
            for (int nt = 0; nt < 8; ++nt) {
                int brow = nt * 16 + colL;
                int bidx = brow * 64 + ((kk0 + 8 * g) ^ ((brow & 7) << 3));
                short8 bh = *(const short8*)&Wh[bidx];
                short8 bl = *(const short8*)&Wl[bidx];
                acc[nt] = __builtin_amdgcn_mfma_f32_16x16x32_bf16(af, bh, acc[nt], 0, 0, 0);
                acc[nt] = __builtin_amdgcn_mfma_f32_16x16x32_bf16(af, bl, acc[nt], 0, 0, 0);
            }
        }
        __syncthreads();
    }

    const int rowb = wvx * 16 + g * 4;
#pragma unroll
    for (int r = 0; r < 4; ++r) {
        int row = rowb + r;
        int rs = (row & 7) << 3;
#pragma unroll
        for (int nt = 0; nt < 8; ++nt) {
            ubuf[row * 128 + ((nt * 16 + colL) ^ rs)] = f2bf(fmaxf(acc[nt][r], 0.f));
        }
    }
    __syncthreads();

    f32x4 acc2[8];
#pragma unroll
    for (int nt = 0; nt < 8; ++nt) {
        float bb = b2[nt * 16 + colL];
        acc2[nt] = (f32x4){bb, bb, bb, bb};
    }
#pragma unroll
    for (int kp2 = 0; kp2 < 2; ++kp2) {
        ((int4*)Wh)[tid] = ((const int4*)(w2h + kp2 * 8192))[tid];
        ((int4*)Wh)[tid + 512] = ((const int4*)(w2h + kp2 * 8192))[tid + 512];
        ((int4*)Wl)[tid] = ((const int4*)(w2l + kp2 * 8192))[tid];
        ((int4*)Wl)[tid + 512] = ((const int4*)(w2l + kp2 * 8192))[tid + 512];
        __syncthreads();
#pragma unroll
        for (int ks = 0; ks < 2; ++ks) {
            int kk0 = ks * 32;
            short8 af = *(const short8*)&ubuf[arow * 128 + ((kp2 * 64 + kk0 + 8 * g) ^ aswz)];
#pragma unroll
            for (int nt = 0; nt < 8; ++nt) {
                int brow = nt * 16 + colL;
                int bidx = brow * 64 + ((kk0 + 8 * g) ^ ((brow & 7) << 3));
                short8 bh = *(const short8*)&Wh[bidx];
                short8 bl = *(const short8*)&Wl[bidx];
                acc2[nt] = __builtin_amdgcn_mfma_f32_16x16x32_bf16(af, bh, acc2[nt], 0, 0, 0);
                acc2[nt] = __builtin_amdgcn_mfma_f32_16x16x32_bf16(af, bl, acc2[nt], 0, 0, 0);
            }
        }
        __syncthreads();
    }

#pragma unroll
    for (int r = 0; r < 4; ++r) {
        int n = nbase + rowb + r;
        if (n < NN) {
#pragma unroll
            for (int nt = 0; nt < 8; ++nt)
                hout[(size_t)n * H + nt * 16 + colL] = acc2[nt][r];
        }
    }

    if (PROJ) {
#pragma unroll
        for (int r = 0; r < 4; ++r) {
            int row = rowb + r;
            int rs = (row & 7) << 3;
#pragma unroll
            for (int nt = 0; nt < 8; ++nt) {
                ubuf[row * 128 + ((nt * 16 + colL) ^ rs)] = f2bf(acc2[nt][r]);
            }
        }
        __syncthreads();

        f32x4 accd[8], accs[8];
#pragma unroll
        for (int nt = 0; nt < 8; ++nt) { accd[nt] = (f32x4){0, 0, 0, 0}; accs[nt] = (f32x4){0, 0, 0, 0}; }

        PROJ_ROUND(ubuf, pwdh, pwdl, 0, accd)
        PROJ_ROUND(ubuf, pwdh + 8192, pwdl + 8192, 64, accd)
        PROJ_ROUND(ubuf, pwsh, pwsl, 0, accs)
        PROJ_ROUND(ubuf, pwsh + 8192, pwsl + 8192, 64, accs)

        float b1r[8];
#pragma unroll
        for (int nt = 0; nt < 8; ++nt) b1r[nt] = eb1n[nt * 16 + colL];
#pragma unroll
        for (int r = 0; r < 4; ++r) {
            int n = nbase + rowb + r;
            if (n < NN) {
#pragma unroll
                for (int nt = 0; nt < 8; ++nt) {
                    Pdb[(size_t)n * H + nt * 16 + colL] = f2bf(accd[nt][r] + b1r[nt]);
                    Psb[(size_t)n * H + nt * 16 + colL] = f2bf(accs[nt][r]);
                }
            }
        }
    }
}

__global__ __launch_bounds__(256) void pool_kernel(const float* __restrict__ h,
    const int* __restrict__ batch, float* __restrict__ ssum,
    unsigned int* __restrict__ smaxk, float* __restrict__ cnt)
{
    const int tid = threadIdx.x, j = tid & 127, half = tid >> 7;
    const int nbase = blockIdx.x * 64;
    int cur = -1, rc = 0;
    float s = 0.f, mx = 0.f;
    for (int i = 0; i < 32; ++i) {
        int n = nbase + 2 * i + half;
        if (n >= NN) break;
        int g = batch[n];
        float v = h[(size_t)n * H + j];
        if (g != cur) {
            if (cur >= 0) {
                atomicAdd(&ssum[cur * H + j], s);
                atomicMax(&smaxk[cur * H + j], fkey(mx));
                if (j == 0) atomicAdd(&cnt[cur], (float)rc);
            }
            cur = g; s = v; mx = v; rc = 1;
        } else { s += v; mx = fmaxf(mx, v); rc++; }
    }
    if (cur >= 0) {
        atomicAdd(&ssum[cur * H + j], s);
        atomicMax(&smaxk[cur * H + j], fkey(mx));
        if (j == 0) atomicAdd(&cnt[cur], (float)rc);
    }
}

__global__ __launch_bounds__(128) void readout_kernel(const float* __restrict__ ssum,
    const unsigned int* __restrict__ smaxk, const float* __restrict__ cnt,
    const float* __restrict__ rW1, const float* __restrict__ rb1,
    const float* __restrict__ rW2, const float* __restrict__ rb2,
    const float* __restrict__ rW3, const float* __restrict__ rb3,
    float* __restrict__ out)
{
    __shared__ float p[384], h1[128], h2[64];
    const int g = blockIdx.x, j = threadIdx.x;
    float c = fmaxf(cnt[g], 1.0f);
    float sv = ssum[g * H + j];
    p[j] = sv / c;
    p[128 + j] = funkey(smaxk[g * H + j]);
    p[256 + j] = sv;
    __syncthreads();
    float a = rb1[j];
    for (int k = 0; k < 384; ++k) a = fmaf(p[k], rW1[k * H + j], a);
    h1[j] = fmaxf(a, 0.f);
    __syncthreads();
    if (j < 64) {
        float a2 = rb2[j];
        for (int k = 0; k < 128; ++k) a2 = fmaf(h1[k], rW2[k * 64 + j], a2);
        h2[j] = fmaxf(a2, 0.f);
    }
    __syncthreads();
    if (j < 64) {
        float t = h2[j] * rW3[j];
        for (int off = 32; off; off >>= 1) t += __shfl_down(t, off);
        if (j == 0) {
            float z = t + rb3[0];
            out[g] = z > 20.f ? z : log1pf(expf(z));
        }
    }
}

extern "C" void kernel_launch(void* const* d_in, const int* in_sizes, int n_in,
                              void* d_out, int out_size, void* d_ws, size_t ws_size,
                              hipStream_t stream)
{
    const float* x    = (const float*)d_in[0];
    const float* pos  = (const float*)d_in[1];
    const float* ea   = (const float*)d_in[2];
    const int*   ei   = (const int*)d_in[3];
    const int*   batch= (const int*)d_in[4];
    const float* encW = (const float*)d_in[5];
    const float* encb = (const float*)d_in[6];
    const float* eW1  = (const float*)d_in[7];
    const float* eb1  = (const float*)d_in[8];
    const float* eW2  = (const float*)d_in[9];
    const float* eb2  = (const float*)d_in[10];
    const float* nW1  = (const float*)d_in[11];
    const float* nb1  = (const float*)d_in[12];
    const float* nW2  = (const float*)d_in[13];
    const float* nb2  = (const float*)d_in[14];
    const float* rW1  = (const float*)d_in[15];
    const float* rb1  = (const float*)d_in[16];
    const float* rW2  = (const float*)d_in[17];
    const float* rb2  = (const float*)d_in[18];
    const float* rW3  = (const float*)d_in[19];
    const float* rb3  = (const float*)d_in[20];

    char* w = (char*)d_ws;
    size_t o = 0;
    auto alloc = [&](size_t bytes) -> char* {
        char* p = w + o; o += (bytes + 255) / 256 * 256; return p;
    };
    float* hA   = (float*)alloc((size_t)NN * H * 4);
    float* hB   = (float*)alloc((size_t)NN * H * 4);
    ushort* Pdb = (ushort*)alloc((size_t)NN * H * 2);
    ushort* Psb = (ushort*)alloc((size_t)NN * H * 2);
    float* agg  = (float*)alloc((size_t)NN * H * 4);
    float* d2   = (float*)alloc((size_t)NE * 4);
    float* ssum = (float*)alloc((size_t)NG * H * 4);
    unsigned int* smaxk = (unsigned int*)alloc((size_t)NG * H * 4);
    float* cnt  = (float*)alloc((size_t)NG * 4);
    int*   deg    = (int*)alloc((size_t)NN * 4);
    int*   cursor = (int*)alloc((size_t)NN * 4);
    int*   src_s  = (int*)alloc((size_t)NE * 4);
    int*   dst_s  = (int*)alloc((size_t)NE * 4);
    float* ea_s   = (float*)alloc((size_t)NE * DEA * 4);
    float* d2_s   = (float*)alloc((size_t)NE * 4);
    ushort* w2hi  = (ushort*)alloc((size_t)NL * H * H * 2);
    ushort* w2lo  = (ushort*)alloc((size_t)NL * H * H * 2);
    ushort* nw1hi = (ushort*)alloc((size_t)NL * 256 * H * 2);
    ushort* nw1lo = (ushort*)alloc((size_t)NL * 256 * H * 2);
    ushort* nw2hi = (ushort*)alloc((size_t)NL * H * H * 2);
    ushort* nw2lo = (ushort*)alloc((size_t)NL * H * H * 2);
    ushort* w1dhi = (ushort*)alloc((size_t)NL * H * H * 2);
    ushort* w1dlo = (ushort*)alloc((size_t)NL * H * H * 2);
    ushort* w1shi = (ushort*)alloc((size_t)NL * H * H * 2);
    ushort* w1slo = (ushort*)alloc((size_t)NL * H * H * 2);
    (void)ws_size; (void)in_sizes; (void)n_in; (void)out_size;

    const int NB = (NN + 63) / 64;
    const int NBM = (NN + 127) / 128;
    const int EB = (NE + 255) / 256;

    (void)hipMemsetAsync(deg, 0, (size_t)NN * 4, stream);
    dist2_kernel<<<EB, 256, 0, stream>>>(pos, ei, d2);
    hist_kernel<<<EB, 256, 0, stream>>>(ei, deg);
    scan_kernel<<<1, 1024, 0, stream>>>(deg, cursor);
    scatter_kernel<<<EB, 256, 0, stream>>>(ei, ea, d2, cursor, src_s, dst_s, ea_s, d2_s);

    wprep_kernel<<<dim3(64, NL), 256, 0, stream>>>(eW2, w2hi, w2lo, H, H * H, H * H);
    wprep_kernel<<<dim3(128, NL), 256, 0, stream>>>(nW1, nw1hi, nw1lo, 256, 256 * H, 256 * H);
    wprep_kernel<<<dim3(64, NL), 256, 0, stream>>>(nW2, nw2hi, nw2lo, H, H * H, H * H);
    wprep_kernel<<<dim3(64, NL), 256, 0, stream>>>(eW1, w1dhi, w1dlo, H, 273 * H, H * H);
    wprep_kernel<<<dim3(64, NL), 256, 0, stream>>>(eW1 + 128 * H, w1shi, w1slo, H, 273 * H, H * H);

    encoder_kernel<<<NB, 256, 0, stream>>>(x, encW, encb, hA);

    // layer-0 proj
    proj_mfma_kernel<<<NBM, 512, 0, stream>>>(hA,
        w1dhi, w1dlo, w1shi, w1slo, eb1, Pdb, Psb);

    float* hcur = hA;
    float* hnext = hB;
    for (int l = 0; l < NL; ++l) {
        (void)hipMemsetAsync(agg, 0, (size_t)NN * H * 4, stream);
        edge_mfma_kernel<<<NE / EPB, 512, 0, stream>>>(Pdb, Psb, ea_s, d2_s, src_s, dst_s,
            eW1 + (size_t)l * 273 * H, w2hi + (size_t)l * H * H, w2lo + (size_t)l * H * H,
            eb2 + l * H, agg);
        if (l < NL - 1) {
            int ln = l + 1;
            node_fused_kernel<1><<<NBM, 512, 0, stream>>>(hcur, agg,
                nw1hi + (size_t)l * 256 * H, nw1lo + (size_t)l * 256 * H,
                nw2hi + (size_t)l * H * H, nw2lo + (size_t)l * H * H,
                nb1 + l * H, nb2 + l * H,
                w1dhi + (size_t)ln * H * H, w1dlo + (size_t)ln * H * H,
                w1shi + (size_t)ln * H * H, w1slo + (size_t)ln * H * H,
                eb1 + ln * H, hnext, Pdb, Psb);
        } else {
            node_fused_kernel<0><<<NBM, 512, 0, stream>>>(hcur, agg,
                nw1hi + (size_t)l * 256 * H, nw1lo + (size_t)l * 256 * H,
                nw2hi + (size_t)l * H * H, nw2lo + (size_t)l * H * H,
                nb1 + l * H, nb2 + l * H,
                (const ushort*)nullptr, (const ushort*)nullptr,
                (const ushort*)nullptr, (const ushort*)nullptr,
                (const float*)nullptr, hnext, Pdb, Psb);
        }
        float* tmp = hcur; hcur = hnext; hnext = tmp;
    }

    (void)hipMemsetAsync(ssum, 0, (size_t)NG * H * 4, stream);
    (void)hipMemsetAsync(smaxk, 0, (size_t)NG * H * 4, stream);
    (void)hipMemsetAsync(cnt, 0, (size_t)NG * 4, stream);
    pool_kernel<<<NB, 256, 0, stream>>>(hcur, batch, ssum, smaxk, cnt);
    readout_kernel<<<NG, 128, 0, stream>>>(ssum, smaxk, cnt,
        rW1, rb1, rW2, rb2, rW3, rb3, (float*)d_out);
}